// Round 4
// baseline (142534.583 us; speedup 1.0000x reference)
//
#include <hip/hip_runtime.h>
#include <math.h>

#define T_   1024
#define B_   128
#define H_   512
#define I_   256
#define NWG  192     // 3 gates x 64 col-groups
#define NTH  256
#define NC   8       // columns per workgroup
#define NZR  128     // bar1 arrivers (z+r wgs)
#define NH   64      // bar2 arrivers (h wgs)
#define BS   32      // coherent-load pipeline batch (dwords per thread)

// ---- coherent (cross-XCD) accesses: per-access sc0/sc1, NO cache-wide fences ----
__device__ __forceinline__ float co_ld(const float* p) {
    return __hip_atomic_load(p, __ATOMIC_RELAXED, __HIP_MEMORY_SCOPE_AGENT);
}
__device__ __forceinline__ void co_st(float* p, float v) {
    __hip_atomic_store(p, v, __ATOMIC_RELAXED, __HIP_MEMORY_SCOPE_AGENT);
}

// arrive: __syncthreads() drains all threads' vmcnt (compiler emits
// s_waitcnt vmcnt(0) before s_barrier), so the sc1 data stores are at the
// coherence point before the leader's RELAXED add lands there.
__device__ __forceinline__ void arrive(int* cnt) {
    __syncthreads();
    if (threadIdx.x == 0)
        __hip_atomic_fetch_add(cnt, 1, __ATOMIC_RELAXED, __HIP_MEMORY_SCOPE_AGENT);
}

// all-thread tight poll; monotonic counter so every thread exits consistently
__device__ __forceinline__ void wait_flag(int* cnt, int target) {
    while (__hip_atomic_load(cnt, __ATOMIC_RELAXED, __HIP_MEMORY_SCOPE_AGENT) < target) {}
}

// ---- pipelined coherent GEMM: A from transposed exchange buffer, W from LDS ----
__device__ __forceinline__ void issue_batch(const float* __restrict__ AT, int kbase,
                                            float a[BS]) {
    #pragma unroll
    for (int j = 0; j < BS; ++j)
        a[j] = co_ld(AT + (size_t)(kbase + j) * B_);
}
__device__ __forceinline__ void fma_batch(const float a[BS],
                                          const float* __restrict__ wlds, int kbase,
                                          float acc[NC]) {
    #pragma unroll
    for (int j = 0; j < BS; ++j) {
        const float* wr = wlds + (kbase + j) * NC;
        #pragma unroll
        for (int c = 0; c < NC; ++c) acc[c] = fmaf(a[j], wr[c], acc[c]);
    }
}
// 256 k-values: 8 batches of BS, double-buffered (issue k+1 before consuming k)
__device__ __forceinline__ void accum_coh(const float* __restrict__ AT,
                                          const float* __restrict__ wlds,
                                          float acc[NC]) {
    float a0[BS], a1[BS];
    issue_batch(AT, 0, a0);
    #pragma unroll
    for (int kb = 0; kb < 8; ++kb) {
        if ((kb & 1) == 0) {
            if (kb + 1 < 8) issue_batch(AT, (kb + 1) * BS, a1);
            fma_batch(a0, wlds, kb * BS, acc);
        } else {
            if (kb + 1 < 8) issue_batch(AT, (kb + 1) * BS, a0);
            fma_batch(a1, wlds, kb * BS, acc);
        }
    }
}

// x-projection: input row (normal cached loads, 16-deep batches) x LDS weights
__device__ __forceinline__ void accum_x(const float* __restrict__ xrow,
                                        const float* __restrict__ wlds,
                                        float acc[NC]) {
    const float4* x4 = (const float4*)xrow;
    #pragma unroll
    for (int half = 0; half < 2; ++half) {
        float4 a[16];
        #pragma unroll
        for (int j = 0; j < 16; ++j) a[j] = x4[half * 16 + j];
        #pragma unroll
        for (int j = 0; j < 16; ++j) {
            #pragma unroll
            for (int kk = 0; kk < 4; ++kk) {
                float av = (&a[j].x)[kk];
                const float* wr = wlds + ((half * 16 + j) * 4 + kk) * NC;
                #pragma unroll
                for (int c = 0; c < NC; ++c) acc[c] = fmaf(av, wr[c], acc[c]);
            }
        }
    }
}

// prologue-only: acc[c] += sum_k Arow[k] * W[k][col0+c]  (normal cached loads)
__device__ __forceinline__ void accum_global(const float* __restrict__ Arow,
                                             const float* __restrict__ Wp,
                                             int kn, float acc[NC]) {
    #pragma unroll 2
    for (int k = 0; k < kn; k += 4) {
        float4 a = *(const float4*)(Arow + k);
        const float* w0 = Wp + (size_t)k * H_;
        #pragma unroll
        for (int kk = 0; kk < 4; ++kk) {
            float av = (&a.x)[kk];
            const float* wr = w0 + (size_t)kk * H_;
            #pragma unroll
            for (int c = 0; c < NC; ++c) acc[c] = fmaf(av, wr[c], acc[c]);
        }
    }
}

__device__ __forceinline__ void kh_combine(float acc[NC], float (*red)[NC], int r, int kh) {
    __syncthreads();
    if (kh) {
        float4* p = (float4*)&red[r][0];
        p[0] = make_float4(acc[0], acc[1], acc[2], acc[3]);
        p[1] = make_float4(acc[4], acc[5], acc[6], acc[7]);
    }
    __syncthreads();
    if (!kh) {
        #pragma unroll
        for (int c = 0; c < NC; ++c) acc[c] += red[r][c];
    }
}

__device__ __forceinline__ float sigmoidf_(float x) { return 1.0f / (1.0f + expf(-x)); }

__global__ __launch_bounds__(NTH, 1) void scagru_persist(
    const float* __restrict__ input, const float* __restrict__ state,
    const float* __restrict__ W_zh, const float* __restrict__ W_zx, const float* __restrict__ b_z,
    const float* __restrict__ W_rh, const float* __restrict__ W_rx, const float* __restrict__ b_r,
    const float* __restrict__ W_hh, const float* __restrict__ W_hx, const float* __restrict__ b_h,
    const float* __restrict__ W_ch, const float* __restrict__ b_c,
    float* __restrict__ out,
    float* __restrict__ hT, float* __restrict__ hrT, float* __restrict__ zT,
    int* __restrict__ bar)
{
    const int w    = blockIdx.x;
    const int gate = w >> 6;          // 0:z 1:r 2:h
    const int cg   = w & 63;
    const int col0 = cg * NC;
    const int tid  = threadIdx.x;
    const int r    = tid & 127;       // batch row
    const int kh   = tid >> 7;        // k-half (0/1)

    __shared__ float wh_lds[H_ * NC];   // 16 KB
    __shared__ float wx_lds[I_ * NC];   // 8 KB
    __shared__ float red[B_][NC];       // 4 KB

    const float* Wh = (gate == 0) ? W_zh : (gate == 1) ? W_rh : W_hh;
    const float* Wx = (gate == 0) ? W_zx : (gate == 1) ? W_rx : W_hx;
    const float* bg = (gate == 0) ? b_z  : (gate == 1) ? b_r  : b_h;

    int* cnt1 = bar;        // z/r arrive after phase A
    int* cnt2 = bar + 32;   // h arrives after phase B (separate cache line)

    // ---- stage weight slices into LDS (one time) ----
    for (int i = tid; i < H_ * NC; i += NTH)
        wh_lds[i] = Wh[(size_t)(i >> 3) * H_ + col0 + (i & 7)];
    for (int i = tid; i < I_ * NC; i += NTH)
        wx_lds[i] = Wx[(size_t)(i >> 3) * H_ + col0 + (i & 7)];

    // ---- context slice + fold gate bias ----
    float cctx[NC];
    {
        float acc[NC];
        #pragma unroll
        for (int c = 0; c < NC; ++c) acc[c] = 0.f;
        accum_global(state + (size_t)r * H_ + kh * 256,
                     W_ch + (size_t)(kh * 256) * H_ + col0, 256, acc);
        kh_combine(acc, red, r, kh);
        if (!kh) {
            #pragma unroll
            for (int c = 0; c < NC; ++c)
                cctx[c] = fmaxf(acc[c] + b_c[col0 + c], 0.f) + bg[col0 + c];
        }
    }

    // ---- h-wgs publish initial h (transposed, coherent) ----
    if (gate == 2) {
        if (!kh) {
            #pragma unroll
            for (int c = 0; c < NC; ++c)
                co_st(hT + (size_t)(col0 + c) * B_ + r, state[(size_t)r * H_ + col0 + c]);
        }
        arrive(cnt2);
    }

    // ---- x-projection prefetch for t=0 ----
    float accx[NC];
    #pragma unroll
    for (int c = 0; c < NC; ++c) accx[c] = 0.f;
    accum_x(input + (size_t)r * I_ + kh * 128, wx_lds + (size_t)(kh * 128) * NC, accx);

    for (int t = 0; t < T_; ++t) {
        if (gate < 2) {
            // ---------------- phase A: z / r ----------------
            wait_flag(cnt2, NH * (t + 1));
            float hv[NC];
            if (gate == 1 && !kh) {          // prefetch h for r*h (hides under GEMM)
                #pragma unroll
                for (int c = 0; c < NC; ++c)
                    hv[c] = co_ld(hT + (size_t)(col0 + c) * B_ + r);
            }
            float acc[NC];
            #pragma unroll
            for (int c = 0; c < NC; ++c) acc[c] = accx[c];
            accum_coh(hT + (size_t)(kh * 256) * B_ + r,
                      wh_lds + (size_t)(kh * 256) * NC, acc);
            kh_combine(acc, red, r, kh);
            if (!kh) {
                if (gate == 0) {
                    #pragma unroll
                    for (int c = 0; c < NC; ++c)
                        co_st(zT + (size_t)(col0 + c) * B_ + r, sigmoidf_(acc[c] + cctx[c]));
                } else {
                    #pragma unroll
                    for (int c = 0; c < NC; ++c)
                        co_st(hrT + (size_t)(col0 + c) * B_ + r,
                              sigmoidf_(acc[c] + cctx[c]) * hv[c]);
                }
            }
            arrive(cnt1);
            if (t + 1 < T_) {
                #pragma unroll
                for (int c = 0; c < NC; ++c) accx[c] = 0.f;
                accum_x(input + (size_t)(t + 1) * B_ * I_ + (size_t)r * I_ + kh * 128,
                        wx_lds + (size_t)(kh * 128) * NC, accx);
            }
        } else {
            // ---------------- phase B: h-candidate + update ----------------
            wait_flag(cnt1, NZR * (t + 1));
            float zz[NC], hh[NC];
            if (!kh) {                        // prefetch blend operands
                #pragma unroll
                for (int c = 0; c < NC; ++c) {
                    zz[c] = co_ld(zT + (size_t)(col0 + c) * B_ + r);
                    hh[c] = co_ld(hT + (size_t)(col0 + c) * B_ + r);
                }
            }
            float acc[NC];
            #pragma unroll
            for (int c = 0; c < NC; ++c) acc[c] = accx[c];
            accum_coh(hrT + (size_t)(kh * 256) * B_ + r,
                      wh_lds + (size_t)(kh * 256) * NC, acc);
            kh_combine(acc, red, r, kh);
            if (!kh) {
                #pragma unroll
                for (int c = 0; c < NC; ++c) {
                    float hc = tanhf(acc[c] + cctx[c]);
                    float hn = (1.f - zz[c]) * hh[c] + zz[c] * hc;
                    co_st(hT + (size_t)(col0 + c) * B_ + r, hn);
                    if (t == T_ - 1) out[(size_t)r * H_ + col0 + c] = hn;
                }
            }
            arrive(cnt2);
            if (t + 1 < T_) {
                #pragma unroll
                for (int c = 0; c < NC; ++c) accx[c] = 0.f;
                accum_x(input + (size_t)(t + 1) * B_ * I_ + (size_t)r * I_ + kh * 128,
                        wx_lds + (size_t)(kh * 128) * NC, accx);
            }
        }
    }
}

extern "C" void kernel_launch(void* const* d_in, const int* in_sizes, int n_in,
                              void* d_out, int out_size, void* d_ws, size_t ws_size,
                              hipStream_t stream)
{
    const float* input = (const float*)d_in[0];
    const float* state = (const float*)d_in[1];
    const float* W_zh  = (const float*)d_in[2];
    const float* W_zx  = (const float*)d_in[3];
    const float* b_z   = (const float*)d_in[4];
    const float* W_rh  = (const float*)d_in[5];
    const float* W_rx  = (const float*)d_in[6];
    const float* b_r   = (const float*)d_in[7];
    const float* W_hh  = (const float*)d_in[8];
    const float* W_hx  = (const float*)d_in[9];
    const float* b_h   = (const float*)d_in[10];
    const float* W_ch  = (const float*)d_in[11];
    const float* b_c   = (const float*)d_in[12];

    float* out = (float*)d_out;
    float* ws  = (float*)d_ws;

    const size_t HB = (size_t)H_ * B_;           // 65536
    float* hT  = ws;
    float* hrT = ws + HB;
    float* zT  = ws + 2 * HB;
    int*   bar = (int*)((char*)d_ws + 3 * HB * sizeof(float));

    hipMemsetAsync(bar, 0, 256, stream);

    scagru_persist<<<dim3(NWG), dim3(NTH), 0, stream>>>(
        input, state,
        W_zh, W_zx, b_z, W_rh, W_rx, b_r, W_hh, W_hx, b_h, W_ch, b_c,
        out, hT, hrT, zT, bar);
}

// Round 5
// 41267.584 us; speedup vs baseline: 3.4539x; 3.4539x over previous
//
#include <hip/hip_runtime.h>
#include <math.h>

#define T_   1024
#define B_   128
#define H_   512
#define I_   256
#define NWG  192     // 3 gates x 64 col-groups
#define NTH  256
#define NC   8       // columns per workgroup

// ---- coherent (cross-XCD) accesses: per-access, NO cache-wide fences, NO RMW ----
__device__ __forceinline__ float co_ld(const float* p) {
    return __hip_atomic_load(p, __ATOMIC_RELAXED, __HIP_MEMORY_SCOPE_AGENT);
}
__device__ __forceinline__ void co_st(float* p, float v) {
    __hip_atomic_store(p, v, __ATOMIC_RELAXED, __HIP_MEMORY_SCOPE_AGENT);
}
__device__ __forceinline__ int co_ldi(const int* p) {
    return __hip_atomic_load(p, __ATOMIC_RELAXED, __HIP_MEMORY_SCOPE_AGENT);
}
__device__ __forceinline__ void co_sti(int* p, int v) {
    __hip_atomic_store(p, v, __ATOMIC_RELAXED, __HIP_MEMORY_SCOPE_AGENT);
}

// publish: __syncthreads() drains each wave's vmcnt (compiler emits
// s_waitcnt vmcnt(0) before s_barrier) so this block's sc1 data stores are at
// the coherence point; then the leader writes this wg's OWN slot (plain store,
// no RMW -> no MALL serialization).
__device__ __forceinline__ void publish(int* slot, int v) {
    __syncthreads();
    if (threadIdx.x == 0) co_sti(slot, v);
}

// steady-state h-side GEMM: A from transposed coherent buffer, W from LDS
// (EXACT v2 form -- known-good caching; do not restructure)
__device__ __forceinline__ void accum_coh(const float* __restrict__ AT,
                                          const float* __restrict__ wlds,
                                          float acc[NC]) {
    #pragma unroll 4
    for (int k = 0; k < 256; ++k) {
        float av = co_ld(AT + (size_t)k * B_);
        const float* wr = wlds + k * NC;
        #pragma unroll
        for (int c = 0; c < NC; ++c) acc[c] = fmaf(av, wr[c], acc[c]);
    }
}

// x-projection: input row (normal cached float4) x LDS weights (v2 form)
__device__ __forceinline__ void accum_x(const float* __restrict__ xrow,
                                        const float* __restrict__ wlds,
                                        float acc[NC]) {
    #pragma unroll 2
    for (int k = 0; k < 128; k += 4) {
        float4 a = *(const float4*)(xrow + k);
        #pragma unroll
        for (int kk = 0; kk < 4; ++kk) {
            float av = (&a.x)[kk];
            const float* wr = wlds + (k + kk) * NC;
            #pragma unroll
            for (int c = 0; c < NC; ++c) acc[c] = fmaf(av, wr[c], acc[c]);
        }
    }
}

// prologue-only: acc[c] += sum_k Arow[k] * W[k][col0+c]  (normal cached loads)
__device__ __forceinline__ void accum_global(const float* __restrict__ Arow,
                                             const float* __restrict__ Wp,
                                             int kn, float acc[NC]) {
    #pragma unroll 2
    for (int k = 0; k < kn; k += 4) {
        float4 a = *(const float4*)(Arow + k);
        const float* w0 = Wp + (size_t)k * H_;
        #pragma unroll
        for (int kk = 0; kk < 4; ++kk) {
            float av = (&a.x)[kk];
            const float* wr = w0 + (size_t)kk * H_;
            #pragma unroll
            for (int c = 0; c < NC; ++c) acc[c] = fmaf(av, wr[c], acc[c]);
        }
    }
}

__device__ __forceinline__ void kh_combine(float acc[NC], float (*red)[NC], int r, int kh) {
    __syncthreads();
    if (kh) {
        float4* p = (float4*)&red[r][0];
        p[0] = make_float4(acc[0], acc[1], acc[2], acc[3]);
        p[1] = make_float4(acc[4], acc[5], acc[6], acc[7]);
    }
    __syncthreads();
    if (!kh) {
        #pragma unroll
        for (int c = 0; c < NC; ++c) acc[c] += red[r][c];
    }
}

__device__ __forceinline__ float sigmoidf_(float x) { return 1.0f / (1.0f + expf(-x)); }

__global__ __launch_bounds__(NTH, 1) void scagru_persist(
    const float* __restrict__ input, const float* __restrict__ state,
    const float* __restrict__ W_zh, const float* __restrict__ W_zx, const float* __restrict__ b_z,
    const float* __restrict__ W_rh, const float* __restrict__ W_rx, const float* __restrict__ b_r,
    const float* __restrict__ W_hh, const float* __restrict__ W_hx, const float* __restrict__ b_h,
    const float* __restrict__ W_ch, const float* __restrict__ b_c,
    float* __restrict__ out,
    float* __restrict__ hT, float* __restrict__ hrT, float* __restrict__ zT,
    int* __restrict__ bar)
{
    const int w    = blockIdx.x;
    const int gate = w >> 6;          // 0:z 1:r 2:h
    const int cg   = w & 63;
    const int col0 = cg * NC;
    const int tid  = threadIdx.x;
    const int r    = tid & 127;       // batch row
    const int kh   = tid >> 7;        // k-half (0/1)

    __shared__ float wh_lds[H_ * NC];   // 16 KB
    __shared__ float wx_lds[I_ * NC];   // 8 KB
    __shared__ float red[B_][NC];       // 4 KB

    const float* Wh = (gate == 0) ? W_zh : (gate == 1) ? W_rh : W_hh;
    const float* Wx = (gate == 0) ? W_zx : (gate == 1) ? W_rx : W_hx;
    const float* bg = (gate == 0) ? b_z  : (gate == 1) ? b_r  : b_h;

    // per-wg slot arrays (distinct words; no RMW anywhere)
    int* hslot = bar;          // [64]  h-wg cg publishes h_t with value t+1 (h_0 -> 1)
    int* zslot = bar + 64;     // [64]  z-wg cg publishes step t with value t+1
    int* rslot = bar + 128;    // [64]  r-wg cg publishes step t with value t+1

    // ---- stage weight slices into LDS (one time) ----
    for (int i = tid; i < H_ * NC; i += NTH)
        wh_lds[i] = Wh[(size_t)(i >> 3) * H_ + col0 + (i & 7)];
    for (int i = tid; i < I_ * NC; i += NTH)
        wx_lds[i] = Wx[(size_t)(i >> 3) * H_ + col0 + (i & 7)];

    // ---- context slice + fold gate bias ----
    float cctx[NC];
    {
        float acc[NC];
        #pragma unroll
        for (int c = 0; c < NC; ++c) acc[c] = 0.f;
        accum_global(state + (size_t)r * H_ + kh * 256,
                     W_ch + (size_t)(kh * 256) * H_ + col0, 256, acc);
        kh_combine(acc, red, r, kh);
        if (!kh) {
            #pragma unroll
            for (int c = 0; c < NC; ++c)
                cctx[c] = fmaxf(acc[c] + b_c[col0 + c], 0.f) + bg[col0 + c];
        }
    }

    // ---- h-wgs publish initial h (transposed, coherent) ----
    if (gate == 2) {
        if (!kh) {
            #pragma unroll
            for (int c = 0; c < NC; ++c)
                co_st(hT + (size_t)(col0 + c) * B_ + r, state[(size_t)r * H_ + col0 + c]);
        }
        publish(&hslot[cg], 1);
    }

    // ---- x-projection prefetch for t=0 ----
    float accx[NC];
    #pragma unroll
    for (int c = 0; c < NC; ++c) accx[c] = 0.f;
    accum_x(input + (size_t)r * I_ + kh * 128, wx_lds + (size_t)(kh * 128) * NC, accx);

    for (int t = 0; t < T_; ++t) {
        if (gate < 2) {
            // ---------------- phase A: z / r ----------------
            // wait: h_t published by all 64 h-wgs (value t+1)
            if (tid < 64) {
                const int* s = &hslot[tid];
                while (co_ldi(s) < t + 1) {}
            }
            __syncthreads();

            float hv[NC];
            if (gate == 1 && !kh) {          // prefetch h for r*h (hides under GEMM)
                #pragma unroll
                for (int c = 0; c < NC; ++c)
                    hv[c] = co_ld(hT + (size_t)(col0 + c) * B_ + r);
            }
            float acc[NC];
            #pragma unroll
            for (int c = 0; c < NC; ++c) acc[c] = accx[c];
            accum_coh(hT + (size_t)(kh * 256) * B_ + r,
                      wh_lds + (size_t)(kh * 256) * NC, acc);
            kh_combine(acc, red, r, kh);
            if (!kh) {
                if (gate == 0) {
                    #pragma unroll
                    for (int c = 0; c < NC; ++c)
                        co_st(zT + (size_t)(col0 + c) * B_ + r, sigmoidf_(acc[c] + cctx[c]));
                } else {
                    #pragma unroll
                    for (int c = 0; c < NC; ++c)
                        co_st(hrT + (size_t)(col0 + c) * B_ + r,
                              sigmoidf_(acc[c] + cctx[c]) * hv[c]);
                }
            }
            publish(gate == 0 ? &zslot[cg] : &rslot[cg], t + 1);

            if (t + 1 < T_) {
                #pragma unroll
                for (int c = 0; c < NC; ++c) accx[c] = 0.f;
                accum_x(input + (size_t)(t + 1) * B_ * I_ + (size_t)r * I_ + kh * 128,
                        wx_lds + (size_t)(kh * 128) * NC, accx);
            }
        } else {
            // ---------------- phase B: h-candidate + update ----------------
            // wait: ALL 128 z/r wgs done with step t (they read all hT columns,
            // so h may not be overwritten before every one has published — WAR)
            if (tid < 64) {
                const int* s = &rslot[tid];
                while (co_ldi(s) < t + 1) {}
            } else if (tid < 128) {
                const int* s = &zslot[tid - 64];
                while (co_ldi(s) < t + 1) {}
            }
            __syncthreads();

            float zz[NC], hh[NC];
            if (!kh) {                        // prefetch blend operands
                #pragma unroll
                for (int c = 0; c < NC; ++c) {
                    zz[c] = co_ld(zT + (size_t)(col0 + c) * B_ + r);
                    hh[c] = co_ld(hT + (size_t)(col0 + c) * B_ + r);
                }
            }
            float acc[NC];
            #pragma unroll
            for (int c = 0; c < NC; ++c) acc[c] = accx[c];
            accum_coh(hrT + (size_t)(kh * 256) * B_ + r,
                      wh_lds + (size_t)(kh * 256) * NC, acc);
            kh_combine(acc, red, r, kh);
            if (!kh) {
                #pragma unroll
                for (int c = 0; c < NC; ++c) {
                    float hc = tanhf(acc[c] + cctx[c]);
                    float hn = (1.f - zz[c]) * hh[c] + zz[c] * hc;
                    co_st(hT + (size_t)(col0 + c) * B_ + r, hn);
                    if (t == T_ - 1) out[(size_t)r * H_ + col0 + c] = hn;
                }
            }
            publish(&hslot[cg], t + 2);

            if (t + 1 < T_) {
                #pragma unroll
                for (int c = 0; c < NC; ++c) accx[c] = 0.f;
                accum_x(input + (size_t)(t + 1) * B_ * I_ + (size_t)r * I_ + kh * 128,
                        wx_lds + (size_t)(kh * 128) * NC, accx);
            }
        }
    }
}

extern "C" void kernel_launch(void* const* d_in, const int* in_sizes, int n_in,
                              void* d_out, int out_size, void* d_ws, size_t ws_size,
                              hipStream_t stream)
{
    const float* input = (const float*)d_in[0];
    const float* state = (const float*)d_in[1];
    const float* W_zh  = (const float*)d_in[2];
    const float* W_zx  = (const float*)d_in[3];
    const float* b_z   = (const float*)d_in[4];
    const float* W_rh  = (const float*)d_in[5];
    const float* W_rx  = (const float*)d_in[6];
    const float* b_r   = (const float*)d_in[7];
    const float* W_hh  = (const float*)d_in[8];
    const float* W_hx  = (const float*)d_in[9];
    const float* b_h   = (const float*)d_in[10];
    const float* W_ch  = (const float*)d_in[11];
    const float* b_c   = (const float*)d_in[12];

    float* out = (float*)d_out;
    float* ws  = (float*)d_ws;

    const size_t HB = (size_t)H_ * B_;           // 65536
    float* hT  = ws;
    float* hrT = ws + HB;
    float* zT  = ws + 2 * HB;
    int*   bar = (int*)((char*)d_ws + 3 * HB * sizeof(float));

    hipMemsetAsync(bar, 0, 1024, stream);

    scagru_persist<<<dim3(NWG), dim3(NTH), 0, stream>>>(
        input, state,
        W_zh, W_zx, b_z, W_rh, W_rx, b_r, W_hh, W_hx, b_h, W_ch, b_c,
        out, hT, hrT, zT, bar);
}